// Round 12
// baseline (1356.133 us; speedup 1.0000x reference)
//
#include <hip/hip_runtime.h>
#include <math.h>

// B=64, T=1000, S=96, A=32, INP=128, H=256. All I/O fp32.
// d_ws: pre fp16 [2][64000][256] = 65,536,000 B | frag tables 655,360 B after.

typedef _Float16 half2_t __attribute__((ext_vector_type(2)));
typedef __attribute__((ext_vector_type(8))) short bf16x8;   // 8 bf16 in 4 regs
typedef __attribute__((ext_vector_type(4))) float f32x4;

__device__ __forceinline__ short f2bf(float f) {     // fp32 -> bf16 (RNE)
    unsigned u = __builtin_bit_cast(unsigned, f);
    return (short)((u + 0x7FFFu + ((u >> 16) & 1u)) >> 16);
}

// Barrier WITHOUT the vmcnt(0) drain __syncthreads() inserts (LDS-only comms).
__device__ __forceinline__ void barrier_lds() {
    __asm__ __volatile__("s_waitcnt lgkmcnt(0)" ::: "memory");
    __builtin_amdgcn_s_barrier();
}

// ---------------------------------------------------------------------------
// Kernel 0: pre-swizzle weights into MFMA fragment tables (bf16).
// All three groups share the same gather: entry(lane) = 8 k-consecutive
// values of one non-k index (A and B frag layouts have identical per-lane
// gather: lane&15 = non-k index, lane>>4 = k-quad).
//  e <  8192 : G1 B-frags, Wa (fc11_w/fc21_w), K=128
//  e < 24576 : G2 B-frags, Wi (W_ih1/W_ih2),  K=256
//  e < 40960 : A -frags,  W_hh^T: A[j][k] = W_hh[k][j]
// ---------------------------------------------------------------------------
__global__ __launch_bounds__(256, 1)
void prep_kernel(const float* __restrict__ fc11_w, const float* __restrict__ W_ih1,
                 const float* __restrict__ fc21_w, const float* __restrict__ W_ih2,
                 const float* __restrict__ W_hh1, const float* __restrict__ W_hh2,
                 short* __restrict__ tab)
{
    const int e    = blockIdx.x * 256 + threadIdx.x;   // 160*256 = 40960 entries
    const int lane = e & 63;
    const int q = lane >> 4, m = lane & 15;
    const float* W;
    int k0, n;
    if (e < 8192) {                       // G1
        int t_ = e >> 6;
        int ks = t_ & 3, nt = (t_ >> 2) & 15, br = t_ >> 6;
        W = br ? fc21_w : fc11_w;
        k0 = ks * 32 + q * 8; n = nt * 16 + m;
    } else if (e < 24576) {               // G2
        int t_ = (e - 8192) >> 6;
        int ks = t_ & 7, nt = (t_ >> 3) & 15, br = t_ >> 7;
        W = br ? W_ih2 : W_ih1;
        k0 = ks * 32 + q * 8; n = nt * 16 + m;
    } else {                              // A-frags for rnn (W_hh^T)
        int f = (e - 24576) >> 6;
        int kt = f & 7, mt = (f >> 3) & 3, w = (f >> 5) & 3, br = f >> 7;
        W = br ? W_hh2 : W_hh1;
        k0 = kt * 32 + q * 8; n = w * 64 + mt * 16 + m;
    }
    bf16x8 v;
#pragma unroll
    for (int j = 0; j < 8; ++j) v[j] = f2bf(W[(size_t)(k0 + j) * 256 + n]);
    ((bf16x8*)tab)[e] = v;
}

// ---------------------------------------------------------------------------
// Kernel 1: feed-forward via MFMA (unchanged R8 structure). pre layout:
// [br][b*1000+t][j] fp16 row-major.
// ---------------------------------------------------------------------------
__global__ __launch_bounds__(256, 2)
void ff_kernel(const float* __restrict__ state,
               const float* __restrict__ action,
               const float* __restrict__ fc11_b, const float* __restrict__ fc21_b,
               const float* __restrict__ b_hh1, const float* __restrict__ b_ih1,
               const float* __restrict__ b_hh2, const float* __restrict__ b_ih2,
               const short* __restrict__ tab,
               _Float16* __restrict__ pre_out)
{
    __shared__ short X1[128 * 264];       // 67.6 KB bf16, +8 pad per row

    const int tile = blockIdx.x % 500;
    const int br   = blockIdx.x / 500;
    const int tid  = threadIdx.x;
    const int w    = tid >> 6;
    const int lane = tid & 63;
    const int q = lane >> 4, m = lane & 15;
    const int row0 = tile * 128;

    const float* ba = br ? fc21_b : fc11_b;
    const float* bh = br ? b_hh2 : b_hh1;
    const float* bi = br ? b_ih2 : b_ih1;
    const bf16x8* tG1 = (const bf16x8*)tab + (size_t)br * 4096;
    const bf16x8* tG2 = (const bf16x8*)tab + 8192 + (size_t)br * 8192;

    float ba_v[16], bb_v[16];
#pragma unroll
    for (int nt = 0; nt < 16; ++nt) {
        int c = nt * 16 + m;
        ba_v[nt] = ba[c];
        bb_v[nt] = bh[c] + bi[c];
    }

    bf16x8 af[2][4];
#pragma unroll
    for (int mt = 0; mt < 2; ++mt) {
        const int rw = row0 + 64 * mt + 16 * w + m;
#pragma unroll
        for (int ks = 0; ks < 4; ++ks) {
            int k0 = ks * 32 + q * 8;
            const float* src = (k0 < 96) ? (state  + (size_t)rw * 96 + k0)
                                         : (action + (size_t)rw * 32 + (k0 - 96));
            float4 x0 = *(const float4*)src;
            float4 x1 = *(const float4*)(src + 4);
            bf16x8 a;
            a[0] = f2bf(x0.x); a[1] = f2bf(x0.y); a[2] = f2bf(x0.z); a[3] = f2bf(x0.w);
            a[4] = f2bf(x1.x); a[5] = f2bf(x1.y); a[6] = f2bf(x1.z); a[7] = f2bf(x1.w);
            af[mt][ks] = a;
        }
    }

#pragma unroll 4
    for (int nt = 0; nt < 16; ++nt) {
        bf16x8 bf[4];
#pragma unroll
        for (int ks = 0; ks < 4; ++ks) bf[ks] = tG1[(nt * 4 + ks) * 64 + lane];
#pragma unroll
        for (int mt = 0; mt < 2; ++mt) {
            f32x4 acc = {0.f, 0.f, 0.f, 0.f};
#pragma unroll
            for (int ks = 0; ks < 4; ++ks)
                acc = __builtin_amdgcn_mfma_f32_16x16x32_bf16(af[mt][ks], bf[ks], acc, 0, 0, 0);
#pragma unroll
            for (int r = 0; r < 4; ++r) {     // D: col=lane&15, row=q*4+r
                float v = acc[r] + ba_v[nt];
                v = v > 0.f ? v : 0.f;
                X1[(64 * mt + 16 * w + q * 4 + r) * 264 + nt * 16 + m] = f2bf(v);
            }
        }
    }
    // X1 rows for wave w's m-tiles written+read by THIS wave only -> no barrier.

    bf16x8 a2[2][8];
#pragma unroll
    for (int mt = 0; mt < 2; ++mt)
#pragma unroll
        for (int ks = 0; ks < 8; ++ks)
            a2[mt][ks] = *(const bf16x8*)&X1[(64 * mt + 16 * w + m) * 264 + ks * 32 + q * 8];

    _Float16* pre = pre_out + (size_t)br * 64000u * 256u;
#pragma unroll 2
    for (int nt = 0; nt < 16; ++nt) {
        bf16x8 bg[8];
#pragma unroll
        for (int ks = 0; ks < 8; ++ks) bg[ks] = tG2[(nt * 8 + ks) * 64 + lane];
#pragma unroll
        for (int mt = 0; mt < 2; ++mt) {
            f32x4 acc = {0.f, 0.f, 0.f, 0.f};
#pragma unroll
            for (int ks = 0; ks < 8; ++ks)
                acc = __builtin_amdgcn_mfma_f32_16x16x32_bf16(a2[mt][ks], bg[ks], acc, 0, 0, 0);
#pragma unroll
            for (int r = 0; r < 4; ++r) {
                float v = acc[r] + bb_v[nt];
                pre[(size_t)(row0 + 64 * mt + 16 * w + q * 4 + r) * 256 + nt * 16 + m] = (_Float16)v;
            }
        }
    }
}

// ---------------------------------------------------------------------------
// Kernel 2: MFMA recurrence. Grid = 8 workgroups x 256 threads; each handles
// 16 chains (g = br*4 + group; chains = (g&3)*16 + 0..15).
//   z^T = W_hh^T . h^T : A = W^T (j rows, AGPR-resident frags),
//                        B = h   (cols = chains, LDS, lane-sequential chunks)
// Wave w owns j-slice [64w,64w+64) = 4 m-tiles x 8 k-tiles = 32 MFMA/step.
// D C-layout: col = chain (lane&15), rows = 4 consecutive j -> b64 LDS write.
// pre preloaded into MFMA C operand. Double-buffered h, ONE barrier/step.
// q head fused: per-lane partial + shfl + LDS qpart + wave0 store.
// ---------------------------------------------------------------------------
__global__ __launch_bounds__(256)
__attribute__((amdgpu_waves_per_eu(1, 1)))
void rnn_kernel(const _Float16* __restrict__ pre_all,
                const float* __restrict__ hn,
                const short* __restrict__ tabA,
                const float* __restrict__ fc12_w, const float* __restrict__ fc12_b,
                const float* __restrict__ fc22_w, const float* __restrict__ fc22_b,
                float* __restrict__ out)
{
    __shared__ short hlds[2][8][4][16][8];   // [buf][kt][q][chain][jj] bf16, 16 KB
    __shared__ float qpart[2][4][16];        // [parity][wave][chain]

    const int g    = blockIdx.x;       // 0..7
    const int br   = g >> 2;
    const int gb   = g & 3;
    const int tid  = threadIdx.x;
    const int wv   = tid >> 6;         // wave = j-slice [64wv, 64wv+64)
    const int lane = tid & 63;
    const int q    = lane >> 4;
    const int mm   = lane & 15;        // chain index within group (n-col)
    const int cl   = gb * 16 + mm;     // batch id of this lane's chain

    // ---- A-frags (W_hh^T), 32 x bf16x8, pinned to AGPR file ----
    const bf16x8* tA = (const bf16x8*)tabA;
    bf16x8 af[4][8];
#pragma unroll
    for (int mt = 0; mt < 4; ++mt)
#pragma unroll
        for (int kt = 0; kt < 8; ++kt)
            af[mt][kt] = tA[(size_t)((((br * 4 + wv) * 4 + mt) * 8) + kt) * 64 + lane];
#pragma unroll
    for (int mt = 0; mt < 4; ++mt)
#pragma unroll
        for (int kt = 0; kt < 8; ++kt)
            __asm__ __volatile__("" : "+a"(af[mt][kt]));   // AGPR-resident, no remat

    // q-head weights for this lane's 16 j values
    const float* qwp = br ? fc22_w : fc12_w;
    const float  qb  = br ? fc22_b[0] : fc12_b[0];
    f32x4 qw[4];
#pragma unroll
    for (int mt = 0; mt < 4; ++mt)
        qw[mt] = *(const f32x4*)&qwp[wv * 64 + mt * 16 + q * 4];

    // ---- init h buf0 from hn (shared h0 across branches) ----
    for (int idx = tid; idx < 16 * 256; idx += 256) {
        int m = idx >> 8, j = idx & 255;
        hlds[0][j >> 5][(j >> 3) & 3][m][j & 7] = f2bf(hn[(gb * 16 + m) * 256 + j]);
    }

    // pre: row = cl*1000 + t, j-offset per m-tile
    const _Float16* pre = pre_all + ((size_t)br * 64000 + (size_t)cl * 1000) * 256;
    const int joff = wv * 64 + q * 4;
    uint2 pc[4], pn[4];
#pragma unroll
    for (int mt = 0; mt < 4; ++mt) {
        pc[mt] = *(const uint2*)(pre + joff + mt * 16);
        pn[mt] = *(const uint2*)(pre + 256 + joff + mt * 16);
    }

    barrier_lds();

    for (int tt = 0; tt < 1000; ++tt) {
        const int pp = tt & 1;
        const int t2 = (tt + 2 < 1000) ? (tt + 2) : 999;
        uint2 pn2[4];
#pragma unroll
        for (int mt = 0; mt < 4; ++mt)
            pn2[mt] = *(const uint2*)(pre + (size_t)t2 * 256 + joff + mt * 16);

        // B-frags: lane-sequential 16-B chunks, conflict-free
        bf16x8 bh[8];
#pragma unroll
        for (int kt = 0; kt < 8; ++kt)
            bh[kt] = *(const bf16x8*)&hlds[pp][kt][q][mm][0];

        // acc init = pre (C operand), then 8-deep MFMA chains x 4 m-tiles
        f32x4 z[4];
#pragma unroll
        for (int mt = 0; mt < 4; ++mt) {
            half2_t lo = __builtin_bit_cast(half2_t, pc[mt].x);
            half2_t hi = __builtin_bit_cast(half2_t, pc[mt].y);
            z[mt] = f32x4{(float)lo[0], (float)lo[1], (float)hi[0], (float)hi[1]};
        }
#pragma unroll
        for (int kt = 0; kt < 8; ++kt)
#pragma unroll
            for (int mt = 0; mt < 4; ++mt)
                z[mt] = __builtin_amdgcn_mfma_f32_16x16x32_bf16(af[mt][kt], bh[kt], z[mt], 0, 0, 0);

        // sigmoid + q partial + pack + publish h_new
        float qp = 0.f;
#pragma unroll
        for (int mt = 0; mt < 4; ++mt) {
            float h0 = 1.0f / (1.0f + __expf(-z[mt].x));
            float h1 = 1.0f / (1.0f + __expf(-z[mt].y));
            float h2 = 1.0f / (1.0f + __expf(-z[mt].z));
            float h3 = 1.0f / (1.0f + __expf(-z[mt].w));
            qp += h0 * qw[mt].x + h1 * qw[mt].y + h2 * qw[mt].z + h3 * qw[mt].w;
            unsigned d0 = (unsigned)(unsigned short)f2bf(h0) |
                          ((unsigned)(unsigned short)f2bf(h1) << 16);
            unsigned d1 = (unsigned)(unsigned short)f2bf(h2) |
                          ((unsigned)(unsigned short)f2bf(h3) << 16);
            const int j0m = wv * 64 + mt * 16 + q * 4;   // 4-aligned
            *(uint2*)&hlds[pp ^ 1][j0m >> 5][(j0m >> 3) & 3][mm][j0m & 7] = uint2{d0, d1};
        }
        qp += __shfl_xor(qp, 16, 64);
        qp += __shfl_xor(qp, 32, 64);
        if (lane < 16) qpart[pp][wv][mm] = qp;

        barrier_lds();                  // publish h_new + qpart; no vm drain

        if (wv == 0 && lane < 16) {
            float qv = qpart[pp][0][mm] + qpart[pp][1][mm] +
                       qpart[pp][2][mm] + qpart[pp][3][mm] + qb;
            out[(size_t)br * 64000 + (size_t)cl * 1000 + tt] = qv;   // in flight
        }

#pragma unroll
        for (int mt = 0; mt < 4; ++mt) { pc[mt] = pn[mt]; pn[mt] = pn2[mt]; }
    }
}

// ---------------------------------------------------------------------------
extern "C" void kernel_launch(void* const* d_in, const int* in_sizes, int n_in,
                              void* d_out, int out_size, void* d_ws, size_t ws_size,
                              hipStream_t stream)
{
    const float* state  = (const float*)d_in[0];
    const float* action = (const float*)d_in[1];
    const float* hn     = (const float*)d_in[2];
    const float* fc11_w = (const float*)d_in[3];
    const float* fc11_b = (const float*)d_in[4];
    const float* W_hh1  = (const float*)d_in[5];
    const float* W_ih1  = (const float*)d_in[6];
    const float* b_hh1  = (const float*)d_in[7];
    const float* b_ih1  = (const float*)d_in[8];
    const float* fc12_w = (const float*)d_in[9];
    const float* fc12_b = (const float*)d_in[10];
    const float* fc21_w = (const float*)d_in[11];
    const float* fc21_b = (const float*)d_in[12];
    const float* W_hh2  = (const float*)d_in[13];
    const float* W_ih2  = (const float*)d_in[14];
    const float* b_hh2  = (const float*)d_in[15];
    const float* b_ih2  = (const float*)d_in[16];
    const float* fc22_w = (const float*)d_in[17];
    const float* fc22_b = (const float*)d_in[18];

    _Float16* pre = (_Float16*)d_ws;                         // 65,536,000 B
    short* tab = (short*)((char*)d_ws + 65536000u);          // 655,360 B (flat, no aliasing)

    prep_kernel<<<160, 256, 0, stream>>>(fc11_w, W_ih1, fc21_w, W_ih2,
                                         W_hh1, W_hh2, tab);
    ff_kernel<<<1000, 256, 0, stream>>>(state, action,
                                        fc11_b, fc21_b, b_hh1, b_ih1,
                                        b_hh2, b_ih2, tab, pre);
    rnn_kernel<<<8, 256, 0, stream>>>(pre, hn, tab + 24576 * 8,
                                      fc12_w, fc12_b, fc22_w, fc22_b,
                                      (float*)d_out);
}

// Round 13
// 789.095 us; speedup vs baseline: 1.7186x; 1.7186x over previous
//
#include <hip/hip_runtime.h>
#include <math.h>

// B=64, T=1000, S=96, A=32, INP=128, H=256. All I/O fp32.
// d_ws: pre fp16 [2][64000][256] = 65,536,000 B | h fp16 same = 65,536,000 B.
// MFMA frag tables (393,216 B) in the TAIL of the h region (consumed by ff
// BEFORE rnn writes h). rnn weight table wtab (262,144 B) lives in D_OUT
// (512 KB): written by wprep, read during rnn, fully overwritten by q_kernel.

typedef _Float16 half2_t __attribute__((ext_vector_type(2)));
typedef __attribute__((ext_vector_type(8))) short bf16x8;   // 8 bf16 in 4 regs
typedef __attribute__((ext_vector_type(4))) float f32x4;

__device__ __forceinline__ float fdot2(half2_t a, half2_t b, float c) {
#if __has_builtin(__builtin_amdgcn_fdot2)
    return __builtin_amdgcn_fdot2(a, b, c, false);   // v_dot2_f32_f16
#else
    return c + (float)a[0] * (float)b[0] + (float)a[1] * (float)b[1];
#endif
}

__device__ __forceinline__ short f2bf(float f) {     // fp32 -> bf16 (RNE)
    unsigned u = __builtin_bit_cast(unsigned, f);
    return (short)((u + 0x7FFFu + ((u >> 16) & 1u)) >> 16);
}

__device__ __forceinline__ unsigned packh2(float a, float b) {
    return __builtin_bit_cast(unsigned, half2_t{(_Float16)a, (_Float16)b});
}

// Barrier WITHOUT the vmcnt(0) drain __syncthreads() inserts (LDS-only comms).
__device__ __forceinline__ void barrier_lds() {
    __asm__ __volatile__("s_waitcnt lgkmcnt(0)" ::: "memory");
    __builtin_amdgcn_s_barrier();
}

// ---------------------------------------------------------------------------
// Kernel 0a: pre-swizzle Wa/Wi into MFMA B-fragment tables (bf16). (R8 form)
// ---------------------------------------------------------------------------
__global__ __launch_bounds__(256, 1)
void prep_kernel(const float* __restrict__ fc11_w, const float* __restrict__ W_ih1,
                 const float* __restrict__ fc21_w, const float* __restrict__ W_ih2,
                 short* __restrict__ tab)
{
    const int e    = blockIdx.x * 256 + threadIdx.x;   // 96*256 = 24576 entries
    const int lane = e & 63;
    const int q = lane >> 4, m = lane & 15;
    const float* W;
    int k0, n;
    if (e < 8192) {                       // G1: Wa, K=128
        int t_ = e >> 6;
        int ks = t_ & 3, nt = (t_ >> 2) & 15, br = t_ >> 6;
        W = br ? fc21_w : fc11_w;
        k0 = ks * 32 + q * 8; n = nt * 16 + m;
    } else {                              // G2: Wi, K=256
        int t_ = (e - 8192) >> 6;
        int ks = t_ & 7, nt = (t_ >> 3) & 15, br = t_ >> 7;
        W = br ? W_ih2 : W_ih1;
        k0 = ks * 32 + q * 8; n = nt * 16 + m;
    }
    bf16x8 v;
#pragma unroll
    for (int j = 0; j < 8; ++j) v[j] = f2bf(W[(size_t)(k0 + j) * 256 + n]);
    ((bf16x8*)tab)[e] = v;
}

// ---------------------------------------------------------------------------
// Kernel 0b: pre-convert W_hh to per-thread-contiguous half2 table.
// Thread t of branch br (R10 mapping: k0=(t>>6)*32, c0=(t&63)*4) owns 64
// uints = whb[c][i] = half2(W[k0+2i][c0+c], W[k0+2i+1][c0+c]), c<4, i<16.
// Per-step reload in rnn becomes 16 clean dwordx4 (256 B/thread, was 512 B
// fp32 + ~128 cvt/pack VALU -> the measured 1450 cyc/step bottleneck).
// ---------------------------------------------------------------------------
__global__ __launch_bounds__(512, 1)
void wprep_kernel(const float* __restrict__ W_hh1, const float* __restrict__ W_hh2,
                  unsigned* __restrict__ wtab)
{
    const int br = blockIdx.x;
    const int t  = threadIdx.x;
    const float* Whh = br ? W_hh2 : W_hh1;
    const int k0 = (t >> 6) * 32;
    const int c0 = (t & 63) * 4;
    unsigned* dst = wtab + ((size_t)br * 512 + t) * 64u;
#pragma unroll
    for (int i = 0; i < 16; ++i) {
        float4 lo = *(const float4*)(Whh + (size_t)(k0 + 2 * i) * 256 + c0);
        float4 hi = *(const float4*)(Whh + (size_t)(k0 + 2 * i + 1) * 256 + c0);
        dst[0 * 16 + i] = packh2(lo.x, hi.x);
        dst[1 * 16 + i] = packh2(lo.y, hi.y);
        dst[2 * 16 + i] = packh2(lo.z, hi.z);
        dst[3 * 16 + i] = packh2(lo.w, hi.w);
    }
}

// ---------------------------------------------------------------------------
// Kernel 1: feed-forward via MFMA (unchanged R8). 128-row blocks, 2 m-tiles
// per wave, b-frags reused across m-tiles.
// ---------------------------------------------------------------------------
__global__ __launch_bounds__(256, 2)
void ff_kernel(const float* __restrict__ state,
               const float* __restrict__ action,
               const float* __restrict__ fc11_b, const float* __restrict__ fc21_b,
               const float* __restrict__ b_hh1, const float* __restrict__ b_ih1,
               const float* __restrict__ b_hh2, const float* __restrict__ b_ih2,
               const short* __restrict__ tab,
               _Float16* __restrict__ pre_out)
{
    __shared__ short X1[128 * 264];       // 67.6 KB bf16, +8 pad per row

    const int tile = blockIdx.x % 500;
    const int br   = blockIdx.x / 500;
    const int tid  = threadIdx.x;
    const int w    = tid >> 6;
    const int lane = tid & 63;
    const int q = lane >> 4, m = lane & 15;
    const int row0 = tile * 128;

    const float* ba = br ? fc21_b : fc11_b;
    const float* bh = br ? b_hh2 : b_hh1;
    const float* bi = br ? b_ih2 : b_ih1;
    const bf16x8* tG1 = (const bf16x8*)tab + (size_t)br * 4096;
    const bf16x8* tG2 = (const bf16x8*)tab + 8192 + (size_t)br * 8192;

    float ba_v[16], bb_v[16];
#pragma unroll
    for (int nt = 0; nt < 16; ++nt) {
        int c = nt * 16 + m;
        ba_v[nt] = ba[c];
        bb_v[nt] = bh[c] + bi[c];
    }

    bf16x8 af[2][4];
#pragma unroll
    for (int mt = 0; mt < 2; ++mt) {
        const int rw = row0 + 64 * mt + 16 * w + m;
#pragma unroll
        for (int ks = 0; ks < 4; ++ks) {
            int k0 = ks * 32 + q * 8;
            const float* src = (k0 < 96) ? (state  + (size_t)rw * 96 + k0)
                                         : (action + (size_t)rw * 32 + (k0 - 96));
            float4 x0 = *(const float4*)src;
            float4 x1 = *(const float4*)(src + 4);
            bf16x8 a;
            a[0] = f2bf(x0.x); a[1] = f2bf(x0.y); a[2] = f2bf(x0.z); a[3] = f2bf(x0.w);
            a[4] = f2bf(x1.x); a[5] = f2bf(x1.y); a[6] = f2bf(x1.z); a[7] = f2bf(x1.w);
            af[mt][ks] = a;
        }
    }

#pragma unroll 4
    for (int nt = 0; nt < 16; ++nt) {
        bf16x8 bf[4];
#pragma unroll
        for (int ks = 0; ks < 4; ++ks) bf[ks] = tG1[(nt * 4 + ks) * 64 + lane];
#pragma unroll
        for (int mt = 0; mt < 2; ++mt) {
            f32x4 acc = {0.f, 0.f, 0.f, 0.f};
#pragma unroll
            for (int ks = 0; ks < 4; ++ks)
                acc = __builtin_amdgcn_mfma_f32_16x16x32_bf16(af[mt][ks], bf[ks], acc, 0, 0, 0);
#pragma unroll
            for (int r = 0; r < 4; ++r) {     // D: col=lane&15, row=q*4+r
                float v = acc[r] + ba_v[nt];
                v = v > 0.f ? v : 0.f;
                X1[(64 * mt + 16 * w + q * 4 + r) * 264 + nt * 16 + m] = f2bf(v);
            }
        }
    }
    // X1 rows for wave w's m-tiles written+read by THIS wave only -> no barrier.

    bf16x8 a2[2][8];
#pragma unroll
    for (int mt = 0; mt < 2; ++mt)
#pragma unroll
        for (int ks = 0; ks < 8; ++ks)
            a2[mt][ks] = *(const bf16x8*)&X1[(64 * mt + 16 * w + m) * 264 + ks * 32 + q * 8];

    _Float16* pre = pre_out + (size_t)br * 64000u * 256u;
#pragma unroll 2
    for (int nt = 0; nt < 16; ++nt) {
        bf16x8 bg[8];
#pragma unroll
        for (int ks = 0; ks < 8; ++ks) bg[ks] = tG2[(nt * 8 + ks) * 64 + lane];
#pragma unroll
        for (int mt = 0; mt < 2; ++mt) {
            f32x4 acc = {0.f, 0.f, 0.f, 0.f};
#pragma unroll
            for (int ks = 0; ks < 8; ++ks)
                acc = __builtin_amdgcn_mfma_f32_16x16x32_bf16(a2[mt][ks], bg[ks], acc, 0, 0, 0);
#pragma unroll
            for (int r = 0; r < 4; ++r) {
                float v = acc[r] + bb_v[nt];
                pre[(size_t)(row0 + 64 * mt + 16 * w + q * 4 + r) * 256 + nt * 16 + m] = (_Float16)v;
            }
        }
    }
}

// ---------------------------------------------------------------------------
// Kernel 2: recurrence, R10 shape (8-way K-split, 512 threads, 128 blocks,
// 2 waves/SIMD). CHANGE vs R10: weights come from the pre-converted half2
// table (per-thread-contiguous 256 B). The compiler's per-step re-stream —
// unavoidable per R6-R11 — now costs half the bytes and zero cvt/pack VALU.
// ---------------------------------------------------------------------------
__global__ __launch_bounds__(512, 2)
void rnn_kernel(const _Float16* __restrict__ pre_all,
                const float* __restrict__ hn,
                const unsigned* __restrict__ wtab,
                _Float16* __restrict__ h_out)
{
    __shared__ _Float16 hbuf[256];
    __shared__ float part[2][8][256];   // [parity][kslice][col] = 16 KB

    const int wg = blockIdx.x;          // 0..127 = chain
    const int br = wg >> 6;
    const int b  = wg & 63;
    const _Float16* pre = pre_all + ((size_t)br * 64000u + (size_t)b * 1000u) * 256u;
    _Float16* hg = h_out + ((size_t)br * 64000u + (size_t)b * 1000u) * 256u;

    const int t    = threadIdx.x;       // 0..511
    const int w    = t >> 6;            // 0..7 = k-slice
    const int lane = t & 63;
    const int k0   = w * 32;
    const int c0   = lane * 4;          // 4 cols per lane
    const int cr   = (w << 5) + (lane & 31);   // reduce col of this lane

    // weights: 64 uints (= whb[c][i] layout), per-thread contiguous in wtab
    const unsigned* wt = wtab + ((size_t)br * 512 + t) * 64u;
    unsigned whb[4][16];
#pragma unroll
    for (int i = 0; i < 64; ++i)
        ((unsigned*)whb)[i] = wt[i];    // compiler: 16x dwordx4

    if (t < 256) hbuf[t] = (_Float16)hn[b * 256 + t];
    barrier_lds();

    float pre_c = (float)pre[cr];
    float pre_n = (float)pre[256 + cr];

    for (int tt = 0; tt < 1000; ++tt) {
        const int t2 = (tt + 2 < 1000) ? (tt + 2) : 999;
        const float pre_n2 = (float)pre[(size_t)t2 * 256 + cr];

        // partial dot over own 32-k slice, 4 cols
        const float4* hb = (const float4*)&hbuf[k0];
        float s0 = 0.f, s1 = 0.f, s2 = 0.f, s3 = 0.f;
#pragma unroll
        for (int k = 0; k < 4; ++k) {
            float4 v = hb[k];                       // 8 halves, wave-broadcast
            const half2_t* hh = (const half2_t*)&v;
#define WH(c, idx) __builtin_bit_cast(half2_t, whb[c][idx])
#pragma unroll
            for (int p = 0; p < 4; ++p) {
                s0 = fdot2(hh[p], WH(0, 4 * k + p), s0);
                s1 = fdot2(hh[p], WH(1, 4 * k + p), s1);
                s2 = fdot2(hh[p], WH(2, 4 * k + p), s2);
                s3 = fdot2(hh[p], WH(3, 4 * k + p), s3);
            }
#undef WH
        }
        const int pp = tt & 1;
        *(float4*)&part[pp][w][c0] = float4{s0, s1, s2, s3};  // conflict-free b128
        barrier_lds();                              // publish partials

        // reduce col cr (lanes 0-31 own wave w's next-step hbuf slice)
        if (lane < 32) {
            const float* pc = &part[pp][0][cr];     // stride 256 floats per kslice
            float z = ((pc[0 * 256] + pc[1 * 256]) + (pc[2 * 256] + pc[3 * 256]))
                    + ((pc[4 * 256] + pc[5 * 256]) + (pc[6 * 256] + pc[7 * 256]))
                    + pre_c;
            const float h = 1.0f / (1.0f + __expf(-z));
            const _Float16 h16 = (_Float16)h;
            hbuf[cr] = h16;                         // same-wave consumer slice
            hg[(size_t)tt * 256 + cr] = h16;        // in flight across barrier
        }

        pre_c = pre_n;
        pre_n = pre_n2;
    }
}

// ---------------------------------------------------------------------------
// Kernel 3: q head. q[n] = h[n,:] . qw + qb. One thread per output.
// Overwrites ALL of d_out (which temporarily held wtab during rnn).
// ---------------------------------------------------------------------------
__global__ __launch_bounds__(256, 2)
void q_kernel(const _Float16* __restrict__ h_all,
              const float* __restrict__ fc12_w, const float* __restrict__ fc12_b,
              const float* __restrict__ fc22_w, const float* __restrict__ fc22_b,
              float* __restrict__ out)
{
    const int n  = blockIdx.x * 256 + threadIdx.x;    // 500 blocks -> n < 128000
    const int br = (n >= 64000);                      // block-uniform
    const float* qwp = br ? fc22_w : fc12_w;
    const float  qb  = br ? fc22_b[0] : fc12_b[0];

    half2_t qw[128];
#pragma unroll
    for (int i = 0; i < 128; ++i)
        qw[i] = half2_t{(_Float16)qwp[2 * i], (_Float16)qwp[2 * i + 1]};

    const float4* hr = (const float4*)(h_all + (size_t)n * 256u);
    float s0 = qb, s1 = 0.f, s2 = 0.f, s3 = 0.f;
#pragma unroll
    for (int k = 0; k < 32; ++k) {
        float4 v = hr[k];
        const half2_t* hh = (const half2_t*)&v;
        s0 = fdot2(hh[0], qw[4 * k + 0], s0);
        s1 = fdot2(hh[1], qw[4 * k + 1], s1);
        s2 = fdot2(hh[2], qw[4 * k + 2], s2);
        s3 = fdot2(hh[3], qw[4 * k + 3], s3);
    }
    out[n] = (s0 + s1) + (s2 + s3);
}

// ---------------------------------------------------------------------------
extern "C" void kernel_launch(void* const* d_in, const int* in_sizes, int n_in,
                              void* d_out, int out_size, void* d_ws, size_t ws_size,
                              hipStream_t stream)
{
    const float* state  = (const float*)d_in[0];
    const float* action = (const float*)d_in[1];
    const float* hn     = (const float*)d_in[2];
    const float* fc11_w = (const float*)d_in[3];
    const float* fc11_b = (const float*)d_in[4];
    const float* W_hh1  = (const float*)d_in[5];
    const float* W_ih1  = (const float*)d_in[6];
    const float* b_hh1  = (const float*)d_in[7];
    const float* b_ih1  = (const float*)d_in[8];
    const float* fc12_w = (const float*)d_in[9];
    const float* fc12_b = (const float*)d_in[10];
    const float* fc21_w = (const float*)d_in[11];
    const float* fc21_b = (const float*)d_in[12];
    const float* W_hh2  = (const float*)d_in[13];
    const float* W_ih2  = (const float*)d_in[14];
    const float* b_hh2  = (const float*)d_in[15];
    const float* b_ih2  = (const float*)d_in[16];
    const float* fc22_w = (const float*)d_in[17];
    const float* fc22_b = (const float*)d_in[18];

    _Float16* pre = (_Float16*)d_ws;                 // 65,536,000 B
    _Float16* hbg = (_Float16*)d_ws + 32768000u;     // 65,536,000 B
    short* tab = (short*)((char*)d_ws + 130678784u); // 393,216 B, h-tail (ff-only)
    unsigned* wtab = (unsigned*)d_out;               // 262,144 B of the 512 KB out

    prep_kernel<<<96, 256, 0, stream>>>(fc11_w, W_ih1, fc21_w, W_ih2, tab);
    wprep_kernel<<<2, 512, 0, stream>>>(W_hh1, W_hh2, wtab);
    ff_kernel<<<1000, 256, 0, stream>>>(state, action,
                                        fc11_b, fc21_b, b_hh1, b_ih1,
                                        b_hh2, b_ih2, tab, pre);
    rnn_kernel<<<128, 512, 0, stream>>>(pre, hn, wtab, hbg);
    q_kernel<<<500, 256, 0, stream>>>(hbg, fc12_w, fc12_b, fc22_w, fc22_b,
                                      (float*)d_out);
}